// Round 1
// baseline (293.275 us; speedup 1.0000x reference)
//
#include <hip/hip_runtime.h>
#include <math.h>

// ---------------------------------------------------------------------------
// K1: C = X @ W1 (fp32, M=B*S, N=D, K=D), fused epilogue:
//     partial[m, n_tile] = sum_{j in tile} gelu(C[m,j] + b1[j]) * W2[j]
// 64x64 tile, BK=16, 256 threads, 4x4 micro-tile per thread.
// ---------------------------------------------------------------------------
__global__ __launch_bounds__(256) void k1_gemm(
    const float* __restrict__ X, const float* __restrict__ W1,
    const float* __restrict__ b1, const float* __restrict__ W2,
    float* __restrict__ partial, int M, int D, int NT)
{
    __shared__ float As[16 * 68];   // [kk][m], stride 68 (16B-aligned rows, no conflicts)
    __shared__ float Bs[16 * 64];   // [kk][n]
    __shared__ float red[64 * 16];  // epilogue reduction

    const int t  = threadIdx.x;
    const int tr = t >> 4;   // 0..15
    const int tc = t & 15;   // 0..15
    const int m0 = blockIdx.x * 64;
    const int n0 = blockIdx.y * 64;

    float acc[4][4] = {};

    for (int k0 = 0; k0 < D; k0 += 16) {
        // Stage X tile: rows m0..m0+63, cols k0..k0+15 -> As[kk*68 + i]
        #pragma unroll
        for (int p = 0; p < 4; ++p) {
            int i = tr + p * 16;
            As[tc * 68 + i] = X[(size_t)(m0 + i) * D + k0 + tc];
        }
        // Stage W1 tile: rows k0..k0+15, cols n0..n0+63 -> Bs[kk*64 + j]
        #pragma unroll
        for (int p = 0; p < 4; ++p) {
            int kk = (t >> 6) + p * 4;
            int j  = t & 63;
            Bs[kk * 64 + j] = W1[(size_t)(k0 + kk) * D + n0 + j];
        }
        __syncthreads();
        #pragma unroll
        for (int kk = 0; kk < 16; ++kk) {
            float4 a4 = *(const float4*)&As[kk * 68 + tr * 4];
            float4 b4 = *(const float4*)&Bs[kk * 64 + tc * 4];
            acc[0][0] += a4.x * b4.x; acc[0][1] += a4.x * b4.y;
            acc[0][2] += a4.x * b4.z; acc[0][3] += a4.x * b4.w;
            acc[1][0] += a4.y * b4.x; acc[1][1] += a4.y * b4.y;
            acc[1][2] += a4.y * b4.z; acc[1][3] += a4.y * b4.w;
            acc[2][0] += a4.z * b4.x; acc[2][1] += a4.z * b4.y;
            acc[2][2] += a4.z * b4.z; acc[2][3] += a4.z * b4.w;
            acc[3][0] += a4.w * b4.x; acc[3][1] += a4.w * b4.y;
            acc[3][2] += a4.w * b4.z; acc[3][3] += a4.w * b4.w;
        }
        __syncthreads();
    }

    // Epilogue: per-row partial sum of gelu(c + b1) * W2 over this 64-col tile
    float4 w2v = *(const float4*)&W2[n0 + tc * 4];
    float4 b1v = *(const float4*)&b1[n0 + tc * 4];
    float w2a[4] = {w2v.x, w2v.y, w2v.z, w2v.w};
    float b1a[4] = {b1v.x, b1v.y, b1v.z, b1v.w};
    const float ISQRT2 = 0.70710678118654752f;
    #pragma unroll
    for (int i = 0; i < 4; ++i) {
        float s = 0.f;
        #pragma unroll
        for (int j = 0; j < 4; ++j) {
            float x = acc[i][j] + b1a[j];
            float g = 0.5f * x * (1.0f + erff(x * ISQRT2));
            s += g * w2a[j];
        }
        red[(tr * 4 + i) * 16 + tc] = s;
    }
    __syncthreads();
    if (t < 64) {
        float s = 0.f;
        #pragma unroll
        for (int jj = 0; jj < 16; ++jj) s += red[t * 16 + jj];
        partial[(size_t)(m0 + t) * NT + blockIdx.y] = s;
    }
}

// ---------------------------------------------------------------------------
// K2: per-batch — reduce partials -> logit -> prob; flags (with last_valid=1);
//     block scan -> boundary positions; nb / shortened / actual_lens outputs.
// One block of 256 threads per batch; each thread owns 8 consecutive rows.
// ---------------------------------------------------------------------------
__global__ __launch_bounds__(256) void k2_scan(
    const float* __restrict__ partial, const float* __restrict__ lengths,
    const float* __restrict__ b2p,
    float* __restrict__ out_probs, float* __restrict__ out_short,
    float* __restrict__ out_nb, float* __restrict__ out_lens,
    int* __restrict__ bpos, int* __restrict__ nb_arr,
    int S, int NT, int K)
{
    const int b = blockIdx.x;
    const int t = threadIdx.x;
    const int len = (int)(lengths[b] * (float)S);
    const float b2 = b2p[0];

    __shared__ int cnt[256];
    __shared__ int flags_s[2048];

    const int RP = S / 256;      // 8
    const int base_s = t * RP;
    int local = 0;
    for (int r = 0; r < RP; ++r) {
        int s = base_s + r;
        float sum = b2;
        for (int jt = 0; jt < NT; ++jt)
            sum += partial[(size_t)(b * S + s) * NT + jt];
        float prob = 1.0f / (1.0f + expf(-sum));
        bool v = (s < len);
        out_probs[(size_t)b * S + s] = v ? prob : 0.0f;
        int f = (s == len - 1) ? 1 : ((v && prob > 0.5f) ? 1 : 0);
        flags_s[s] = f;
        local += f;
    }
    cnt[t] = local;
    __syncthreads();
    // Hillis-Steele inclusive scan over cnt[256]
    for (int off = 1; off < 256; off <<= 1) {
        int v = cnt[t];
        int u = (t >= off) ? cnt[t - off] : 0;
        __syncthreads();
        cnt[t] = v + u;
        __syncthreads();
    }
    int excl = cnt[t] - local;
    int total = cnt[255];
    for (int r = 0; r < RP; ++r) {
        int s = base_s + r;
        if (flags_s[s]) { bpos[b * S + excl] = s; ++excl; }
    }
    if (t == 0) {
        nb_arr[b] = total;
        float nbf = (float)total;
        float Kf  = (float)K;
        out_nb[b]   = nbf;
        out_lens[b] = (float)len;
        float sh;
        if (nbf >= Kf - 1.0f)      sh = 1.0f;
        else if (nbf > 0.0f)       sh = (nbf + 1.0f) / Kf;
        else                       sh = 0.0f;
        out_short[b] = sh;
    }
}

// ---------------------------------------------------------------------------
// K3: segment-mean pooling. One block per (b,k); D/4 threads of float4.
// Segment k (< nb) covers rows [bpos[k-1]+1, bpos[k]]; else write zeros.
// ---------------------------------------------------------------------------
__global__ __launch_bounds__(192) void k3_pool(
    const float* __restrict__ X, const int* __restrict__ bpos,
    const int* __restrict__ nb_arr, float* __restrict__ pooled,
    int S, int D, int K)
{
    const int bk = blockIdx.x;
    const int b  = bk / K;
    const int k  = bk - b * K;
    const int t  = threadIdx.x;
    const int nb = nb_arr[b];

    float4 acc = {0.f, 0.f, 0.f, 0.f};
    if (k < nb) {
        int start = (k == 0) ? 0 : (bpos[b * S + k - 1] + 1);
        int end   = bpos[b * S + k] + 1;
        float cntf = (float)(end - start);
        for (int s = start; s < end; ++s) {
            const float4 v = *(const float4*)&X[((size_t)b * S + s) * D + t * 4];
            acc.x += v.x; acc.y += v.y; acc.z += v.z; acc.w += v.w;
        }
        acc.x /= cntf; acc.y /= cntf; acc.z /= cntf; acc.w /= cntf;
    }
    *(float4*)&pooled[((size_t)b * K + k) * D + t * 4] = acc;
}

// ---------------------------------------------------------------------------
extern "C" void kernel_launch(void* const* d_in, const int* in_sizes, int n_in,
                              void* d_out, int out_size, void* d_ws, size_t ws_size,
                              hipStream_t stream) {
    const float* hidden  = (const float*)d_in[0];
    const float* lengths = (const float*)d_in[1];
    const float* W1      = (const float*)d_in[2];
    const float* b1      = (const float*)d_in[3];
    const float* W2      = (const float*)d_in[4];
    const float* b2      = (const float*)d_in[5];

    const int B = in_sizes[1];
    const int D = in_sizes[3];
    const int S = in_sizes[0] / (B * D);
    const int M = B * S;
    const int NT = D / 64;
    const int K = (out_size - B * S - 3 * B) / (B * D);

    float* out_pooled = (float*)d_out;
    float* out_probs  = out_pooled + (size_t)B * K * D;
    float* out_short  = out_probs + (size_t)B * S;
    float* out_nb     = out_short + B;
    float* out_lens   = out_nb + B;

    float* partial = (float*)d_ws;                       // M*NT floats
    int*   bpos    = (int*)(partial + (size_t)M * NT);   // B*S ints
    int*   nb_arr  = bpos + (size_t)B * S;               // B ints

    dim3 g1(M / 64, NT);
    k1_gemm<<<g1, 256, 0, stream>>>(hidden, W1, b1, W2, partial, M, D, NT);
    k2_scan<<<B, 256, 0, stream>>>(partial, lengths, b2, out_probs, out_short,
                                   out_nb, out_lens, bpos, nb_arr, S, NT, K);
    k3_pool<<<B * K, D / 4, 0, stream>>>(hidden, bpos, nb_arr, out_pooled, S, D, K);
}

// Round 4
// 109.012 us; speedup vs baseline: 2.6903x; 2.6903x over previous
//
#include <hip/hip_runtime.h>
#include <math.h>

typedef __bf16 bf16x8 __attribute__((ext_vector_type(8)));
typedef float  f32x4  __attribute__((ext_vector_type(4)));

// Bit-exact fp32 -> (hi,lo) bf16 split. hi = truncation of top 16 bits
// (integer-domain, cannot be folded away); lo = bf16(x - hi) (Sterbenz-exact
// subtract). x ≈ hi + lo with residual <= ~2^-17 |x|.
__device__ inline void split_bits(float x, __bf16& h, __bf16& l) {
    unsigned u = __builtin_bit_cast(unsigned, x);
    h = __builtin_bit_cast(__bf16, (unsigned short)(u >> 16));
    float hf = __builtin_bit_cast(float, u & 0xFFFF0000u);
    l = (__bf16)(x - hf);
}

// ---------------------------------------------------------------------------
// S0: split W1 (fp32 [K][N]) into transposed bf16 hi/lo: W1t*[n*K + k].
// ---------------------------------------------------------------------------
__global__ __launch_bounds__(256) void s0_split_w1(
    const float* __restrict__ W1, __bf16* __restrict__ Wth,
    __bf16* __restrict__ Wtl, int Dn)
{
    __shared__ float tile[32][33];
    const int k0 = blockIdx.x * 32;
    const int n0 = blockIdx.y * 32;
    const int tx = threadIdx.x & 31, ty = threadIdx.x >> 5;  // ty 0..7
    #pragma unroll
    for (int p = 0; p < 4; ++p)
        tile[ty + p * 8][tx] = W1[(size_t)(k0 + ty + p * 8) * Dn + n0 + tx];
    __syncthreads();
    #pragma unroll
    for (int p = 0; p < 4; ++p) {
        const int n = n0 + ty + p * 8, k = k0 + tx;
        float x = tile[tx][ty + p * 8];
        __bf16 h, l;
        split_bits(x, h, l);
        Wth[(size_t)n * Dn + k] = h;
        Wtl[(size_t)n * Dn + k] = l;
    }
}

// ---------------------------------------------------------------------------
// K1: MFMA split-bf16 GEMM (3-term: hh + hl + lh), fused gelu*W2 row-partial
// epilogue. Tile 128x128, BK=32, 256 threads (4 waves 2x2).
// RACE FIX: each wave writes its own partial slot (12 = 6 n-tiles x 2 wc).
// ---------------------------------------------------------------------------
#define BM 128
#define BN 128
#define BK 32
#define NT2 12   // partial slots per row = (D/BN) * 2 wave-columns

__device__ inline float gelu_f(float x) {
    return 0.5f * x * (1.0f + erff(x * 0.70710678118654752f));
}

__global__ __launch_bounds__(256, 2) void k1_mfma(
    const float* __restrict__ X, const __bf16* __restrict__ W1th,
    const __bf16* __restrict__ W1tl, const float* __restrict__ b1,
    const float* __restrict__ W2, float* __restrict__ partial,
    int Kd)
{
    __shared__ __bf16 Ash[BM * BK];
    __shared__ __bf16 Asl[BM * BK];
    __shared__ __bf16 Bsh[BN * BK];
    __shared__ __bf16 Bsl[BN * BK];

    const int t    = threadIdx.x;
    const int lane = t & 63;
    const int w    = t >> 6;
    const int wr   = w >> 1, wc = w & 1;
    const int ln15 = lane & 15, lg = lane >> 4;
    const int m0   = blockIdx.x * BM;
    const int n0   = blockIdx.y * BN;

    const int sr = t >> 1, sc = (t & 1) * 16;

    f32x4 acc[4][4];
    #pragma unroll
    for (int i = 0; i < 4; ++i)
        #pragma unroll
        for (int j = 0; j < 4; ++j)
            acc[i][j] = (f32x4){0.f, 0.f, 0.f, 0.f};

    for (int k0 = 0; k0 < Kd; k0 += BK) {
        // ---- stage A: fp32 -> hi/lo bf16 via bit split ----
        const float* xsrc = X + (size_t)(m0 + sr) * Kd + k0 + sc;
        float xs[16];
        *(float4*)&xs[0]  = *(const float4*)(xsrc + 0);
        *(float4*)&xs[4]  = *(const float4*)(xsrc + 4);
        *(float4*)&xs[8]  = *(const float4*)(xsrc + 8);
        *(float4*)&xs[12] = *(const float4*)(xsrc + 12);
        bf16x8 ah0, ah1, al0, al1;
        #pragma unroll
        for (int i = 0; i < 8; ++i) {
            __bf16 h, l;
            split_bits(xs[i], h, l);
            ah0[i] = h; al0[i] = l;
        }
        #pragma unroll
        for (int i = 0; i < 8; ++i) {
            __bf16 h, l;
            split_bits(xs[8 + i], h, l);
            ah1[i] = h; al1[i] = l;
        }
        *(bf16x8*)&Ash[sr * BK + sc]     = ah0;
        *(bf16x8*)&Ash[sr * BK + sc + 8] = ah1;
        *(bf16x8*)&Asl[sr * BK + sc]     = al0;
        *(bf16x8*)&Asl[sr * BK + sc + 8] = al1;

        // ---- stage B: pre-split bf16, straight copy ----
        const __bf16* bh = W1th + (size_t)(n0 + sr) * Kd + k0 + sc;
        const __bf16* bl = W1tl + (size_t)(n0 + sr) * Kd + k0 + sc;
        *(bf16x8*)&Bsh[sr * BK + sc]     = *(const bf16x8*)(bh);
        *(bf16x8*)&Bsh[sr * BK + sc + 8] = *(const bf16x8*)(bh + 8);
        *(bf16x8*)&Bsl[sr * BK + sc]     = *(const bf16x8*)(bl);
        *(bf16x8*)&Bsl[sr * BK + sc + 8] = *(const bf16x8*)(bl + 8);

        __syncthreads();

        bf16x8 fah[4], fal[4], fbh[4], fbl[4];
        #pragma unroll
        for (int mf = 0; mf < 4; ++mf) {
            const int r = (wr * 64 + mf * 16 + ln15) * BK + lg * 8;
            fah[mf] = *(const bf16x8*)&Ash[r];
            fal[mf] = *(const bf16x8*)&Asl[r];
        }
        #pragma unroll
        for (int nf = 0; nf < 4; ++nf) {
            const int r = (wc * 64 + nf * 16 + ln15) * BK + lg * 8;
            fbh[nf] = *(const bf16x8*)&Bsh[r];
            fbl[nf] = *(const bf16x8*)&Bsl[r];
        }
        #pragma unroll
        for (int mf = 0; mf < 4; ++mf)
            #pragma unroll
            for (int nf = 0; nf < 4; ++nf) {
                acc[mf][nf] = __builtin_amdgcn_mfma_f32_16x16x32_bf16(
                    fah[mf], fbh[nf], acc[mf][nf], 0, 0, 0);
                acc[mf][nf] = __builtin_amdgcn_mfma_f32_16x16x32_bf16(
                    fah[mf], fbl[nf], acc[mf][nf], 0, 0, 0);
                acc[mf][nf] = __builtin_amdgcn_mfma_f32_16x16x32_bf16(
                    fal[mf], fbh[nf], acc[mf][nf], 0, 0, 0);
            }
        __syncthreads();
    }

    // ---- epilogue: per-row sum of gelu(c + b1)*W2 over THIS WAVE's 64 cols.
    //      Each wave writes its own slot: no inter-wave race.
    float b1v[4], w2v[4];
    #pragma unroll
    for (int nf = 0; nf < 4; ++nf) {
        const int n = n0 + wc * 64 + nf * 16 + ln15;
        b1v[nf] = b1[n];
        w2v[nf] = W2[n];
    }
    #pragma unroll
    for (int mf = 0; mf < 4; ++mf)
        #pragma unroll
        for (int j = 0; j < 4; ++j) {
            float s = 0.f;
            #pragma unroll
            for (int nf = 0; nf < 4; ++nf) {
                float c = acc[mf][nf][j] + b1v[nf];
                s += gelu_f(c) * w2v[nf];
            }
            s += __shfl_xor(s, 1);
            s += __shfl_xor(s, 2);
            s += __shfl_xor(s, 4);
            s += __shfl_xor(s, 8);
            if (ln15 == 0) {
                const int m = m0 + wr * 64 + mf * 16 + lg * 4 + j;
                partial[(size_t)m * NT2 + blockIdx.y * 2 + wc] = s;
            }
        }
}

// ---------------------------------------------------------------------------
// K2: per-batch reduce partials -> prob; flags (last_valid=1); scan -> bpos.
// ---------------------------------------------------------------------------
__global__ __launch_bounds__(256) void k2_scan(
    const float* __restrict__ partial, const float* __restrict__ lengths,
    const float* __restrict__ b2p,
    float* __restrict__ out_probs, float* __restrict__ out_short,
    float* __restrict__ out_nb, float* __restrict__ out_lens,
    int* __restrict__ bpos, int* __restrict__ nb_arr,
    int S, int K)
{
    const int b = blockIdx.x;
    const int t = threadIdx.x;
    const int len = (int)(lengths[b] * (float)S);
    const float b2 = b2p[0];

    __shared__ int cnt[256];
    __shared__ int flags_s[2048];

    const int RP = S / 256;
    const int base_s = t * RP;
    int local = 0;
    for (int r = 0; r < RP; ++r) {
        int s = base_s + r;
        float sum = b2;
        for (int jt = 0; jt < NT2; ++jt)
            sum += partial[(size_t)(b * S + s) * NT2 + jt];
        float prob = 1.0f / (1.0f + expf(-sum));
        bool v = (s < len);
        out_probs[(size_t)b * S + s] = v ? prob : 0.0f;
        int f = (s == len - 1) ? 1 : ((v && prob > 0.5f) ? 1 : 0);
        flags_s[s] = f;
        local += f;
    }
    cnt[t] = local;
    __syncthreads();
    for (int off = 1; off < 256; off <<= 1) {
        int v = cnt[t];
        int u = (t >= off) ? cnt[t - off] : 0;
        __syncthreads();
        cnt[t] = v + u;
        __syncthreads();
    }
    int excl = cnt[t] - local;
    int total = cnt[255];
    for (int r = 0; r < RP; ++r) {
        int s = base_s + r;
        if (flags_s[s]) { bpos[b * S + excl] = s; ++excl; }
    }
    if (t == 0) {
        nb_arr[b] = total;
        float nbf = (float)total;
        float Kf  = (float)K;
        out_nb[b]   = nbf;
        out_lens[b] = (float)len;
        float sh;
        if (nbf >= Kf - 1.0f)      sh = 1.0f;
        else if (nbf > 0.0f)       sh = (nbf + 1.0f) / Kf;
        else                       sh = 0.0f;
        out_short[b] = sh;
    }
}

// ---------------------------------------------------------------------------
// K3: segment-mean pooling. One block per (b,k); D/4 threads of float4.
// ---------------------------------------------------------------------------
__global__ __launch_bounds__(192) void k3_pool(
    const float* __restrict__ X, const int* __restrict__ bpos,
    const int* __restrict__ nb_arr, float* __restrict__ pooled,
    int S, int D, int K)
{
    const int bk = blockIdx.x;
    const int b  = bk / K;
    const int k  = bk - b * K;
    const int t  = threadIdx.x;
    const int nb = nb_arr[b];

    float4 acc = {0.f, 0.f, 0.f, 0.f};
    if (k < nb) {
        int start = (k == 0) ? 0 : (bpos[b * S + k - 1] + 1);
        int end   = bpos[b * S + k] + 1;
        float cntf = (float)(end - start);
        for (int s = start; s < end; ++s) {
            const float4 v = *(const float4*)&X[((size_t)b * S + s) * D + t * 4];
            acc.x += v.x; acc.y += v.y; acc.z += v.z; acc.w += v.w;
        }
        acc.x /= cntf; acc.y /= cntf; acc.z /= cntf; acc.w /= cntf;
    }
    *(float4*)&pooled[((size_t)b * K + k) * D + t * 4] = acc;
}

// ---------------------------------------------------------------------------
extern "C" void kernel_launch(void* const* d_in, const int* in_sizes, int n_in,
                              void* d_out, int out_size, void* d_ws, size_t ws_size,
                              hipStream_t stream) {
    const float* hidden  = (const float*)d_in[0];
    const float* lengths = (const float*)d_in[1];
    const float* W1      = (const float*)d_in[2];
    const float* b1      = (const float*)d_in[3];
    const float* W2      = (const float*)d_in[4];
    const float* b2      = (const float*)d_in[5];

    const int B = in_sizes[1];
    const int D = in_sizes[3];
    const int S = in_sizes[0] / (B * D);
    const int M = B * S;
    const int K = (out_size - B * S - 3 * B) / (B * D);

    float* out_pooled = (float*)d_out;
    float* out_probs  = out_pooled + (size_t)B * K * D;
    float* out_short  = out_probs + (size_t)B * S;
    float* out_nb     = out_short + B;
    float* out_lens   = out_nb + B;

    // d_ws: partial (M*NT2 f32) + bpos (B*S i32) + nb (B i32)  ~851 KB
    char* wsp = (char*)d_ws;
    float* partial = (float*)wsp; wsp += (size_t)M * NT2 * sizeof(float);
    int*   bpos    = (int*)wsp;   wsp += (size_t)B * S * sizeof(int);
    int*   nb_arr  = (int*)wsp;   wsp += 256;

    // W1 hi/lo splits: stash in the pooled output region (K3 overwrites it
    // at the end of every call); fall back to ws tail if it doesn't fit.
    const size_t wsplit_bytes = 2 * (size_t)D * D * sizeof(__bf16);
    __bf16* W1th;
    if ((size_t)B * K * D * sizeof(float) >= wsplit_bytes) {
        W1th = (__bf16*)out_pooled;
    } else {
        W1th = (__bf16*)wsp;
    }
    __bf16* W1tl = W1th + (size_t)D * D;

    dim3 gs(D / 32, D / 32);
    s0_split_w1<<<gs, 256, 0, stream>>>(W1, W1th, W1tl, D);

    dim3 g1(M / BM, D / BN);
    k1_mfma<<<g1, 256, 0, stream>>>(hidden, W1th, W1tl, b1, W2, partial, D);

    k2_scan<<<B, 256, 0, stream>>>(partial, lengths, b2, out_probs, out_short,
                                   out_nb, out_lens, bpos, nb_arr, S, K);
    k3_pool<<<B * K, D / 4, 0, stream>>>(hidden, bpos, nb_arr, out_pooled, S, D, K);
}

// Round 5
// 93.780 us; speedup vs baseline: 3.1273x; 1.1624x over previous
//
#include <hip/hip_runtime.h>
#include <math.h>

typedef __bf16 bf16x8 __attribute__((ext_vector_type(8)));
typedef float  f32x4  __attribute__((ext_vector_type(4)));

// Bit-exact fp32 -> (hi,lo) bf16 split. hi = truncation of top 16 bits
// (integer-domain, cannot be folded away); lo = bf16(x - hi) (Sterbenz-exact
// subtract). x ≈ hi + lo with residual <= ~2^-17 |x|.
__device__ inline void split_bits(float x, __bf16& h, __bf16& l) {
    unsigned u = __builtin_bit_cast(unsigned, x);
    h = __builtin_bit_cast(__bf16, (unsigned short)(u >> 16));
    float hf = __builtin_bit_cast(float, u & 0xFFFF0000u);
    l = (__bf16)(x - hf);
}

// ---------------------------------------------------------------------------
// S0: split W1 (fp32 [K][N]) into transposed bf16 hi/lo: W1t*[n*K + k].
// ---------------------------------------------------------------------------
__global__ __launch_bounds__(256) void s0_split_w1(
    const float* __restrict__ W1, __bf16* __restrict__ Wth,
    __bf16* __restrict__ Wtl, int Dn)
{
    __shared__ float tile[32][33];
    const int k0 = blockIdx.x * 32;
    const int n0 = blockIdx.y * 32;
    const int tx = threadIdx.x & 31, ty = threadIdx.x >> 5;  // ty 0..7
    #pragma unroll
    for (int p = 0; p < 4; ++p)
        tile[ty + p * 8][tx] = W1[(size_t)(k0 + ty + p * 8) * Dn + n0 + tx];
    __syncthreads();
    #pragma unroll
    for (int p = 0; p < 4; ++p) {
        const int n = n0 + ty + p * 8, k = k0 + tx;
        float x = tile[tx][ty + p * 8];
        __bf16 h, l;
        split_bits(x, h, l);
        Wth[(size_t)n * Dn + k] = h;
        Wtl[(size_t)n * Dn + k] = l;
    }
}

// ---------------------------------------------------------------------------
// K1: MFMA split-bf16 GEMM (3-term: hh + hl + lh), fused gelu*W2 row-partial
// epilogue. Tile 128x128, BK=32, 256 threads (4 waves 2x2).
// LDS rows padded to 40 bf16 (80 B): bank-group = (5*row + lg) mod 8 covers
// all 8 groups -> fragment ds_read_b128 at the free 2-way floor (was 8-way).
// ---------------------------------------------------------------------------
#define BM 128
#define BN 128
#define BK 32
#define LDA 40   // padded LDS row stride in bf16 elements (80 B)
#define NT2 12   // partial slots per row = (D/BN) * 2 wave-columns

__device__ inline float gelu_f(float x) {
    return 0.5f * x * (1.0f + erff(x * 0.70710678118654752f));
}

__global__ __launch_bounds__(256, 2) void k1_mfma(
    const float* __restrict__ X, const __bf16* __restrict__ W1th,
    const __bf16* __restrict__ W1tl, const float* __restrict__ b1,
    const float* __restrict__ W2, float* __restrict__ partial,
    int Kd)
{
    __shared__ __bf16 Ash[BM * LDA];
    __shared__ __bf16 Asl[BM * LDA];
    __shared__ __bf16 Bsh[BN * LDA];
    __shared__ __bf16 Bsl[BN * LDA];

    const int t    = threadIdx.x;
    const int lane = t & 63;
    const int w    = t >> 6;
    const int wr   = w >> 1, wc = w & 1;
    const int ln15 = lane & 15, lg = lane >> 4;
    const int m0   = blockIdx.x * BM;
    const int n0   = blockIdx.y * BN;

    const int sr = t >> 1, sc = (t & 1) * 16;

    f32x4 acc[4][4];
    #pragma unroll
    for (int i = 0; i < 4; ++i)
        #pragma unroll
        for (int j = 0; j < 4; ++j)
            acc[i][j] = (f32x4){0.f, 0.f, 0.f, 0.f};

    for (int k0 = 0; k0 < Kd; k0 += BK) {
        // ---- stage A: fp32 -> hi/lo bf16 via bit split ----
        const float* xsrc = X + (size_t)(m0 + sr) * Kd + k0 + sc;
        float xs[16];
        *(float4*)&xs[0]  = *(const float4*)(xsrc + 0);
        *(float4*)&xs[4]  = *(const float4*)(xsrc + 4);
        *(float4*)&xs[8]  = *(const float4*)(xsrc + 8);
        *(float4*)&xs[12] = *(const float4*)(xsrc + 12);
        bf16x8 ah0, ah1, al0, al1;
        #pragma unroll
        for (int i = 0; i < 8; ++i) {
            __bf16 h, l;
            split_bits(xs[i], h, l);
            ah0[i] = h; al0[i] = l;
        }
        #pragma unroll
        for (int i = 0; i < 8; ++i) {
            __bf16 h, l;
            split_bits(xs[8 + i], h, l);
            ah1[i] = h; al1[i] = l;
        }
        *(bf16x8*)&Ash[sr * LDA + sc]     = ah0;
        *(bf16x8*)&Ash[sr * LDA + sc + 8] = ah1;
        *(bf16x8*)&Asl[sr * LDA + sc]     = al0;
        *(bf16x8*)&Asl[sr * LDA + sc + 8] = al1;

        // ---- stage B: pre-split bf16, straight copy ----
        const __bf16* bh = W1th + (size_t)(n0 + sr) * Kd + k0 + sc;
        const __bf16* bl = W1tl + (size_t)(n0 + sr) * Kd + k0 + sc;
        *(bf16x8*)&Bsh[sr * LDA + sc]     = *(const bf16x8*)(bh);
        *(bf16x8*)&Bsh[sr * LDA + sc + 8] = *(const bf16x8*)(bh + 8);
        *(bf16x8*)&Bsl[sr * LDA + sc]     = *(const bf16x8*)(bl);
        *(bf16x8*)&Bsl[sr * LDA + sc + 8] = *(const bf16x8*)(bl + 8);

        __syncthreads();

        bf16x8 fah[4], fal[4], fbh[4], fbl[4];
        #pragma unroll
        for (int mf = 0; mf < 4; ++mf) {
            const int r = (wr * 64 + mf * 16 + ln15) * LDA + lg * 8;
            fah[mf] = *(const bf16x8*)&Ash[r];
            fal[mf] = *(const bf16x8*)&Asl[r];
        }
        #pragma unroll
        for (int nf = 0; nf < 4; ++nf) {
            const int r = (wc * 64 + nf * 16 + ln15) * LDA + lg * 8;
            fbh[nf] = *(const bf16x8*)&Bsh[r];
            fbl[nf] = *(const bf16x8*)&Bsl[r];
        }
        #pragma unroll
        for (int mf = 0; mf < 4; ++mf)
            #pragma unroll
            for (int nf = 0; nf < 4; ++nf) {
                acc[mf][nf] = __builtin_amdgcn_mfma_f32_16x16x32_bf16(
                    fah[mf], fbh[nf], acc[mf][nf], 0, 0, 0);
                acc[mf][nf] = __builtin_amdgcn_mfma_f32_16x16x32_bf16(
                    fah[mf], fbl[nf], acc[mf][nf], 0, 0, 0);
                acc[mf][nf] = __builtin_amdgcn_mfma_f32_16x16x32_bf16(
                    fal[mf], fbh[nf], acc[mf][nf], 0, 0, 0);
            }
        __syncthreads();
    }

    // ---- epilogue: per-row sum of gelu(c + b1)*W2 over THIS WAVE's 64 cols.
    float b1v[4], w2v[4];
    #pragma unroll
    for (int nf = 0; nf < 4; ++nf) {
        const int n = n0 + wc * 64 + nf * 16 + ln15;
        b1v[nf] = b1[n];
        w2v[nf] = W2[n];
    }
    #pragma unroll
    for (int mf = 0; mf < 4; ++mf)
        #pragma unroll
        for (int j = 0; j < 4; ++j) {
            float s = 0.f;
            #pragma unroll
            for (int nf = 0; nf < 4; ++nf) {
                float c = acc[mf][nf][j] + b1v[nf];
                s += gelu_f(c) * w2v[nf];
            }
            s += __shfl_xor(s, 1);
            s += __shfl_xor(s, 2);
            s += __shfl_xor(s, 4);
            s += __shfl_xor(s, 8);
            if (ln15 == 0) {
                const int m = m0 + wr * 64 + mf * 16 + lg * 4 + j;
                partial[(size_t)m * NT2 + blockIdx.y * 2 + wc] = s;
            }
        }
}

// ---------------------------------------------------------------------------
// K2: per-batch reduce partials -> prob; flags (last_valid=1); scan -> bpos.
// ---------------------------------------------------------------------------
__global__ __launch_bounds__(256) void k2_scan(
    const float* __restrict__ partial, const float* __restrict__ lengths,
    const float* __restrict__ b2p,
    float* __restrict__ out_probs, float* __restrict__ out_short,
    float* __restrict__ out_nb, float* __restrict__ out_lens,
    int* __restrict__ bpos, int* __restrict__ nb_arr,
    int S, int K)
{
    const int b = blockIdx.x;
    const int t = threadIdx.x;
    const int len = (int)(lengths[b] * (float)S);
    const float b2 = b2p[0];

    __shared__ int cnt[256];
    __shared__ int flags_s[2048];

    const int RP = S / 256;
    const int base_s = t * RP;
    int local = 0;
    for (int r = 0; r < RP; ++r) {
        int s = base_s + r;
        float sum = b2;
        for (int jt = 0; jt < NT2; ++jt)
            sum += partial[(size_t)(b * S + s) * NT2 + jt];
        float prob = 1.0f / (1.0f + expf(-sum));
        bool v = (s < len);
        out_probs[(size_t)b * S + s] = v ? prob : 0.0f;
        int f = (s == len - 1) ? 1 : ((v && prob > 0.5f) ? 1 : 0);
        flags_s[s] = f;
        local += f;
    }
    cnt[t] = local;
    __syncthreads();
    for (int off = 1; off < 256; off <<= 1) {
        int v = cnt[t];
        int u = (t >= off) ? cnt[t - off] : 0;
        __syncthreads();
        cnt[t] = v + u;
        __syncthreads();
    }
    int excl = cnt[t] - local;
    int total = cnt[255];
    for (int r = 0; r < RP; ++r) {
        int s = base_s + r;
        if (flags_s[s]) { bpos[b * S + excl] = s; ++excl; }
    }
    if (t == 0) {
        nb_arr[b] = total;
        float nbf = (float)total;
        float Kf  = (float)K;
        out_nb[b]   = nbf;
        out_lens[b] = (float)len;
        float sh;
        if (nbf >= Kf - 1.0f)      sh = 1.0f;
        else if (nbf > 0.0f)       sh = (nbf + 1.0f) / Kf;
        else                       sh = 0.0f;
        out_short[b] = sh;
    }
}

// ---------------------------------------------------------------------------
// K3: segment-mean pooling. One block per (b,k); D/4 threads of float4.
// ---------------------------------------------------------------------------
__global__ __launch_bounds__(192) void k3_pool(
    const float* __restrict__ X, const int* __restrict__ bpos,
    const int* __restrict__ nb_arr, float* __restrict__ pooled,
    int S, int D, int K)
{
    const int bk = blockIdx.x;
    const int b  = bk / K;
    const int k  = bk - b * K;
    const int t  = threadIdx.x;
    const int nb = nb_arr[b];

    float4 acc = {0.f, 0.f, 0.f, 0.f};
    if (k < nb) {
        int start = (k == 0) ? 0 : (bpos[b * S + k - 1] + 1);
        int end   = bpos[b * S + k] + 1;
        float cntf = (float)(end - start);
        for (int s = start; s < end; ++s) {
            const float4 v = *(const float4*)&X[((size_t)b * S + s) * D + t * 4];
            acc.x += v.x; acc.y += v.y; acc.z += v.z; acc.w += v.w;
        }
        acc.x /= cntf; acc.y /= cntf; acc.z /= cntf; acc.w /= cntf;
    }
    *(float4*)&pooled[((size_t)b * K + k) * D + t * 4] = acc;
}

// ---------------------------------------------------------------------------
extern "C" void kernel_launch(void* const* d_in, const int* in_sizes, int n_in,
                              void* d_out, int out_size, void* d_ws, size_t ws_size,
                              hipStream_t stream) {
    const float* hidden  = (const float*)d_in[0];
    const float* lengths = (const float*)d_in[1];
    const float* W1      = (const float*)d_in[2];
    const float* b1      = (const float*)d_in[3];
    const float* W2      = (const float*)d_in[4];
    const float* b2      = (const float*)d_in[5];

    const int B = in_sizes[1];
    const int D = in_sizes[3];
    const int S = in_sizes[0] / (B * D);
    const int M = B * S;
    const int K = (out_size - B * S - 3 * B) / (B * D);

    float* out_pooled = (float*)d_out;
    float* out_probs  = out_pooled + (size_t)B * K * D;
    float* out_short  = out_probs + (size_t)B * S;
    float* out_nb     = out_short + B;
    float* out_lens   = out_nb + B;

    // d_ws: partial (M*NT2 f32) + bpos (B*S i32) + nb (B i32)  ~851 KB
    char* wsp = (char*)d_ws;
    float* partial = (float*)wsp; wsp += (size_t)M * NT2 * sizeof(float);
    int*   bpos    = (int*)wsp;   wsp += (size_t)B * S * sizeof(int);
    int*   nb_arr  = (int*)wsp;   wsp += 256;

    // W1 hi/lo splits: stash in the pooled output region (K3 overwrites it
    // at the end of every call); fall back to ws tail if it doesn't fit.
    const size_t wsplit_bytes = 2 * (size_t)D * D * sizeof(__bf16);
    __bf16* W1th;
    if ((size_t)B * K * D * sizeof(float) >= wsplit_bytes) {
        W1th = (__bf16*)out_pooled;
    } else {
        W1th = (__bf16*)wsp;
    }
    __bf16* W1tl = W1th + (size_t)D * D;

    dim3 gs(D / 32, D / 32);
    s0_split_w1<<<gs, 256, 0, stream>>>(W1, W1th, W1tl, D);

    dim3 g1(M / BM, D / BN);
    k1_mfma<<<g1, 256, 0, stream>>>(hidden, W1th, W1tl, b1, W2, partial, D);

    k2_scan<<<B, 256, 0, stream>>>(partial, lengths, b2, out_probs, out_short,
                                   out_nb, out_lens, bpos, nb_arr, S, K);
    k3_pool<<<B * K, D / 4, 0, stream>>>(hidden, bpos, nb_arr, out_pooled, S, D, K);
}